// Round 6
// baseline (17.347 us; speedup 1.0000x reference)
//
#include <hip/hip_runtime.h>

// out[b, 3p+r, 3q+c] = 0                  if p == q
//                    = ±H[b, 3p+r, 3q+c]  otherwise,
// sign = -1 iff (u_s[b, max(p,q)] < 0) && ((r==2) XOR (c==2))
//
// R6: canonical copy-bench shape — flat grid-stride loop, 2048 blocks x 256
// threads, one float4 per iteration. Shape-specialized template so every
// division (/D, /D*D, /3) is a compile-time magic-mul. This matches the m13
// copy probe that measured 6.29 TB/s; any remaining delta vs copy is either
// the sign VALU (predicted negligible) or a fixed dispatch-overhead floor.

typedef float v4f __attribute__((ext_vector_type(4)));

template <int D, int N>
__global__ __launch_bounds__(256)
void jflip_flat(const float* __restrict__ H,
                const float* __restrict__ u_s,
                float* __restrict__ out,
                long long nV4) {
    const long long stride = (long long)gridDim.x * blockDim.x;
    long long f = (long long)blockIdx.x * blockDim.x + threadIdx.x;

    constexpr int DD = D * D;

    for (; f < nV4; f += stride) {
        const long long idx = f * 4;
        const int b   = (int)(idx / DD);                 // const divisor
        const int rem = (int)(idx - (long long)b * DD);
        const int R   = rem / D;                         // const divisor
        const int C0  = rem - R * D;

        const int p = R / 3;
        const float r2s = ((R - 3 * p) == 2) ? -1.0f : 1.0f;
        const float* usb = u_s + (long long)b * N;
        const float sp = (usb[p] < 0.0f) ? -1.0f : 1.0f;

        const v4f h = *reinterpret_cast<const v4f*>(H + idx);
        v4f o;
#pragma unroll
        for (int k = 0; k < 4; ++k) {
            const int C = C0 + k;
            const int q = C / 3;
            const float c2s = ((C - 3 * q) == 2) ? -1.0f : 1.0f;
            const float s   = (q > p) ? ((usb[q] < 0.0f) ? -1.0f : 1.0f) : sp;
            const float mult = (s < 0.0f) ? (r2s * c2s) : 1.0f;
            o[k] = (q == p) ? 0.0f : h[k] * mult;
        }
        *reinterpret_cast<v4f*>(out + idx) = o;
    }
}

// Generic fallback (runtime shapes) — same logic, runtime divisions.
__global__ __launch_bounds__(256)
void jflip_flat_gen(const float* __restrict__ H,
                    const float* __restrict__ u_s,
                    float* __restrict__ out,
                    int N, int D, long long nV4) {
    const long long stride = (long long)gridDim.x * blockDim.x;
    long long f = (long long)blockIdx.x * blockDim.x + threadIdx.x;
    const int DD = D * D;

    for (; f < nV4; f += stride) {
        const long long idx = f * 4;
        const int b   = (int)(idx / DD);
        const int rem = (int)(idx - (long long)b * DD);
        const int R   = rem / D;
        const int C0  = rem - R * D;

        const int p = R / 3;
        const float r2s = ((R - 3 * p) == 2) ? -1.0f : 1.0f;
        const float* usb = u_s + (long long)b * N;
        const float sp = (usb[p] < 0.0f) ? -1.0f : 1.0f;

        const v4f h = *reinterpret_cast<const v4f*>(H + idx);
        v4f o;
#pragma unroll
        for (int k = 0; k < 4; ++k) {
            const int C = C0 + k;
            const int q = C / 3;
            const float c2s = ((C - 3 * q) == 2) ? -1.0f : 1.0f;
            const float s   = (q > p) ? ((usb[q] < 0.0f) ? -1.0f : 1.0f) : sp;
            const float mult = (s < 0.0f) ? (r2s * c2s) : 1.0f;
            o[k] = (q == p) ? 0.0f : h[k] * mult;
        }
        *reinterpret_cast<v4f*>(out + idx) = o;
    }
}

extern "C" void kernel_launch(void* const* d_in, const int* in_sizes, int n_in,
                              void* d_out, int out_size, void* d_ws, size_t ws_size,
                              hipStream_t stream) {
    const float* H   = (const float*)d_in[0];
    const float* u_s = (const float*)d_in[1];
    float* out = (float*)d_out;

    // in_sizes[0] = B*(3N)^2 = 9*B*N^2, in_sizes[1] = B*N
    const long long nH  = (long long)in_sizes[0];
    const long long nUs = (long long)in_sizes[1];
    const int N = (int)(nH / (9LL * nUs));   // 512
    const int B = (int)(nUs / N);            // 4
    const int D = 3 * N;                     // 1536

    const long long nV4 = nH / 4;            // total float4 slots
    dim3 block(256);
    dim3 grid(2048);                          // 8 blocks/CU, grid-stride

    if (N == 512 && D == 1536) {
        jflip_flat<1536, 512><<<grid, block, 0, stream>>>(H, u_s, out, nV4);
    } else {
        jflip_flat_gen<<<grid, block, 0, stream>>>(H, u_s, out, N, D, nV4);
    }
}